// Round 15
// baseline (200.787 us; speedup 1.0000x reference)
//
#include <hip/hip_runtime.h>
#include <hip/hip_bf16.h>
#include <cstdint>

static constexpr int   Nb = 2;
static constexpr int   L  = 4800;
static constexpr int   S  = 4800;
static constexpr int   C  = 256;
static constexpr float THR = 0.2f;
static constexpr float SIM_SCALE = 1.0f / 25.6f;   // 1/(sqrt(C)*sqrt(C)*TEMP)
static constexpr unsigned CAND_CAP = 65536;        // hard math bound is 38400 (<=4/row)

using f32x4  = __attribute__((ext_vector_type(4))) float;
using bf16x8 = __attribute__((ext_vector_type(8))) short;
using u32x4  = __attribute__((ext_vector_type(4))) unsigned int;

// ---------------- fp32 -> bf16 (RNE), both inputs; stats zeroing folded in ----------------
__device__ inline unsigned short bf16_rne(float x) {
    unsigned u = __float_as_uint(x);
    unsigned r = (u + 0x7FFFu + ((u >> 16) & 1u)) >> 16;
    return (unsigned short)r;
}

__global__ __launch_bounds__(256) void cvt_bf16(const float* __restrict__ in0,
                                                const float* __restrict__ in1,
                                                unsigned short* __restrict__ out0,
                                                unsigned short* __restrict__ out1,
                                                int n8,
                                                unsigned* __restrict__ stats, int nStats) {
    if (blockIdx.y == 0) {
        int si = blockIdx.x * 256 + threadIdx.x;
        if (si < nStats) stats[si] = 0u;
    }
    const float* in = blockIdx.y ? in1 : in0;
    unsigned short* out = blockIdx.y ? out1 : out0;
    int i = blockIdx.x * 256 + threadIdx.x;
    if (i >= n8) return;
    f32x4 a = *(const f32x4*)(in + (size_t)i * 8);
    f32x4 b = *(const f32x4*)(in + (size_t)i * 8 + 4);
    union { unsigned short us[8]; u32x4 v; } r;
#pragma unroll
    for (int j = 0; j < 4; j++) r.us[j] = bf16_rne(a[j]);
#pragma unroll
    for (int j = 0; j < 4; j++) r.us[4 + j] = bf16_rne(b[j]);
    *(u32x4*)(out + (size_t)i * 8) = r.v;
}

__device__ inline bool border_ok(int idx) {
    int h = idx / 80, w = idx % 80;
    return (h >= 2) & (h < 58) & (w >= 2) & (w < 78);
}

// ---------------- GEMM core, two epilogue modes ----------------
// Tile 192x192 (R13: doubled BM for 1.5x arithmetic intensity per staged byte;
// 1250 blocks, half the staging traffic of R6's 96x192). 4 waves (2x2),
// wave-tile 96x96 = 6x6 frags of mfma 16x16x32 bf16 (swapped operands:
// lane&15 -> l, (lane>>4)*4+r -> s). acc = 144 VGPR.
// Staging: global_load_lds dwordx4, pre-swizzled source, linear LDS dest,
// XOR-swizzled ds_read (rule-21 both-sides pattern). LDS 48 KB.
// XCD-aware bijective block swizzle (T1/m204), rb-outer/cb-inner order
// (R12 proved ordering governs WRITE locality: concurrent blocks must fill
// contiguous row swaths of the row-major output).
// MODE 0: rowSum/colSum of exp(sim) + zero mask region.
// MODE 1: recompute; write conf + row/col bit-max + candidate list.
#define BM 192
#define BN 192
#define BK 64

static constexpr int NWG   = (L / BM) * (S / BN) * Nb;   // 1250
static constexpr int TILE_X = S / BN;                    // 25
static constexpr int TILES_PER_N = (L / BM) * TILE_X;    // 625
static constexpr int XQ = NWG / 8;                       // 156
static constexpr int XR = NWG % 8;                       // 2

__device__ inline void gload16(const void* g, void* l) {
    __builtin_amdgcn_global_load_lds(
        (const __attribute__((address_space(1))) unsigned int*)g,
        (__attribute__((address_space(3))) unsigned int*)l, 16, 0, 0);
}

template <int MODE>
__global__ __launch_bounds__(256) void gemm_pass(
    const unsigned short* __restrict__ Abf,  // [N,L,C]
    const unsigned short* __restrict__ Bbf,  // [N,S,C]
    float* __restrict__ rowSum,              // [N,L]
    float* __restrict__ colSum,              // [N,S]
    float* __restrict__ conf,                // [N,L,S]      (MODE 1)
    float* __restrict__ mask,                // [N,L,S]      (MODE 0: zeroed here)
    unsigned* __restrict__ rowMax,           // [N,L] bits   (MODE 1)
    unsigned* __restrict__ colMax,           // [N,S] bits   (MODE 1)
    unsigned* __restrict__ cnt,              // cand count   (MODE 1)
    unsigned* __restrict__ cand)             // [CAP][2]     (MODE 1)
{
    __shared__ unsigned short As[BM * BK];   // 24 KB
    __shared__ unsigned short Bs[BN * BK];   // 24 KB

    // bijective XCD swizzle (m204): orig%8 -> xcd, contiguous wgid chunk per xcd
    const int orig = blockIdx.x;
    const int xcd  = orig & 7;
    const int idx  = orig >> 3;
    const int wgid = (xcd < XR ? xcd * (XQ + 1) : XR * (XQ + 1) + (xcd - XR) * XQ) + idx;
    const int n    = wgid / TILES_PER_N;
    const int rem  = wgid % TILES_PER_N;
    const int rb   = (rem / TILE_X) * BM;    // rb outer: concurrent blocks share a
    const int cb   = (rem % TILE_X) * BN;    // row-panel -> contiguous output swaths

    const int t  = threadIdx.x;
    const int lane = t & 63;
    const int wid  = t >> 6;
    const int wr = wid >> 1, wc = wid & 1;

    const unsigned short* Ag = Abf + ((size_t)n * L + rb) * C;
    const unsigned short* Bg = Bbf + ((size_t)n * S + cb) * C;

    f32x4 acc[6][6] = {};

    for (int kt = 0; kt < C; kt += BK) {
        // A and B: 1536 16B chunks each (6/thread each)
#pragma unroll
        for (int i = 0; i < 6; i++) {
            int ix = wid * 384 + i * 64 + lane;
            int row = ix >> 3;
            int src = ((ix & 7) ^ (row & 7)) * 8 + kt;
            gload16(Ag + (size_t)row * C + src, &As[(wid * 384 + i * 64) * 8]);
        }
#pragma unroll
        for (int i = 0; i < 6; i++) {
            int ix = wid * 384 + i * 64 + lane;
            int row = ix >> 3;
            int src = ((ix & 7) ^ (row & 7)) * 8 + kt;
            gload16(Bg + (size_t)row * C + src, &Bs[(wid * 384 + i * 64) * 8]);
        }
        __syncthreads();

#pragma unroll
        for (int kk = 0; kk < 2; kk++) {
            const int kElem = kk * 32 + (lane >> 4) * 8;
            bf16x8 b[6];
#pragma unroll
            for (int f = 0; f < 6; f++) {
                int rbi = wc * 96 + f * 16 + (lane & 15);
                b[f] = *(const bf16x8*)&Bs[rbi * 64 + (kElem ^ ((rbi & 7) << 3))];
            }
#pragma unroll
            for (int fi = 0; fi < 6; fi++) {
                int ra = wr * 96 + fi * 16 + (lane & 15);
                bf16x8 a = *(const bf16x8*)&As[ra * 64 + (kElem ^ ((ra & 7) << 3))];
#pragma unroll
                for (int fj = 0; fj < 6; fj++)
                    acc[fi][fj] = __builtin_amdgcn_mfma_f32_16x16x32_bf16(
                        b[fj], a, acc[fi][fj], 0, 0, 0);
            }
        }
        __syncthreads();
    }

    const int rowBase = rb + wr * 96;
    const int colBase = cb + wc * 96;

    if constexpr (MODE == 0) {
        float csum[6][4] = {};
#pragma unroll
        for (int fi = 0; fi < 6; fi++) {
            const int l = rowBase + fi * 16 + (lane & 15);
            float rsum = 0.f;
#pragma unroll
            for (int fj = 0; fj < 6; fj++) {
#pragma unroll
                for (int r = 0; r < 4; r++) {
                    float e = __expf(acc[fi][fj][r] * SIM_SCALE);
                    rsum += e;
                    csum[fj][r] += e;
                }
            }
            rsum += __shfl_xor(rsum, 16);
            rsum += __shfl_xor(rsum, 32);
            if (lane < 16)
                atomicAdd(&rowSum[(size_t)n * L + l], rsum);
        }
#pragma unroll
        for (int fj = 0; fj < 6; fj++)
#pragma unroll
            for (int r = 0; r < 4; r++) {
                float v = csum[fj][r];
                v += __shfl_xor(v, 1);
                v += __shfl_xor(v, 2);
                v += __shfl_xor(v, 4);
                v += __shfl_xor(v, 8);
                if ((lane & 15) == 0)
                    atomicAdd(&colSum[(size_t)n * S + colBase + fj * 16 + ((lane >> 4) << 2) + r], v);
            }
        // zero this block's linear chunk of the mask region
        const f32x4 zero4 = {0.f, 0.f, 0.f, 0.f};
        const size_t mbase = (size_t)wgid * 36864;   // 46.08M / 1250 blocks
#pragma unroll
        for (int i = 0; i < 36; i++)
            *(f32x4*)&mask[mbase + ((size_t)i * 256 + t) * 4] = zero4;
    } else {
        f32x4 invD1[6];
#pragma unroll
        for (int fj = 0; fj < 6; fj++) {
            const int s0 = colBase + fj * 16 + ((lane >> 4) << 2);
            f32x4 d1 = *(const f32x4*)&colSum[(size_t)n * S + s0];
#pragma unroll
            for (int j = 0; j < 4; j++) invD1[fj][j] = 1.0f / d1[j];
        }
        float cmax[6][4] = {};

#pragma unroll
        for (int fi = 0; fi < 6; fi++) {
            const int l = rowBase + fi * 16 + (lane & 15);
            const float invD2 = 1.0f / rowSum[(size_t)n * L + l];
            const bool bl = border_ok(l);
            float rmax = 0.f;
#pragma unroll
            for (int fj = 0; fj < 6; fj++) {
                const int s0 = colBase + fj * 16 + ((lane >> 4) << 2);
                f32x4 cv;
#pragma unroll
                for (int r = 0; r < 4; r++) {
                    float e = __expf(acc[fi][fj][r] * SIM_SCALE);
                    float c = e * e * invD1[fj][r] * invD2;
                    cv[r] = c;
                    rmax = fmaxf(rmax, c);
                    cmax[fj][r] = fmaxf(cmax[fj][r], c);
                    if (c > THR) {                       // rare: <=4 per row possible
                        int s = s0 + r;
                        if (bl && border_ok(s)) {
                            unsigned pos = atomicAdd(cnt, 1u);
                            if (pos < CAND_CAP) {
                                cand[2 * pos]     = (unsigned)(((size_t)n * L + l) * S + s);
                                cand[2 * pos + 1] = __float_as_uint(c);
                            }
                        }
                    }
                }
                *(f32x4*)&conf[((size_t)n * L + l) * S + s0] = cv;
            }
            rmax = fmaxf(rmax, __shfl_xor(rmax, 16));
            rmax = fmaxf(rmax, __shfl_xor(rmax, 32));
            if (lane < 16)
                atomicMax(&rowMax[(size_t)n * L + l], __float_as_uint(rmax));
        }
#pragma unroll
        for (int fj = 0; fj < 6; fj++)
#pragma unroll
            for (int r = 0; r < 4; r++) {
                float v = cmax[fj][r];
                v = fmaxf(v, __shfl_xor(v, 1));
                v = fmaxf(v, __shfl_xor(v, 2));
                v = fmaxf(v, __shfl_xor(v, 4));
                v = fmaxf(v, __shfl_xor(v, 8));
                if ((lane & 15) == 0)
                    atomicMax(&colMax[(size_t)n * S + colBase + fj * 16 + ((lane >> 4) << 2) + r],
                              __float_as_uint(v));
            }
    }
}

// ---------------- scatter the mutual-NN survivors ----------------
__global__ __launch_bounds__(256) void mask_scatter(
    const unsigned* __restrict__ cnt,
    const unsigned* __restrict__ cand,
    const unsigned* __restrict__ rowMax,
    const unsigned* __restrict__ colMax,
    float* __restrict__ mask)
{
    unsigned nc = *cnt;
    if (nc > CAND_CAP) nc = CAND_CAP;
    for (unsigned i = blockIdx.x * 256 + threadIdx.x; i < nc; i += gridDim.x * 256) {
        unsigned flat = cand[2 * i];
        unsigned bits = cand[2 * i + 1];
        unsigned row = flat / S;          // n*L + l
        unsigned s   = flat % S;
        unsigned n   = row / L;
        if (bits == rowMax[row] && bits == colMax[n * S + s])
            mask[flat] = 1.0f;
    }
}

// ---------------- launch ----------------
extern "C" void kernel_launch(void* const* d_in, const int* in_sizes, int n_in,
                              void* d_out, int out_size, void* d_ws, size_t ws_size,
                              hipStream_t stream) {
    (void)in_sizes; (void)n_in; (void)out_size; (void)ws_size;
    const float* f0 = (const float*)d_in[0];
    const float* f1 = (const float*)d_in[1];

    float* conf = (float*)d_out;                       // N*L*S f32
    float* mask = conf + (size_t)Nb * L * S;

    unsigned short* Abf = (unsigned short*)d_ws;       // 4.92 MB
    unsigned short* Bbf = Abf + (size_t)Nb * L * C;    // 4.92 MB
    float* rowSum = (float*)(Bbf + (size_t)Nb * S * C);
    float* colSum = rowSum + (size_t)Nb * L;
    unsigned* rowMax = (unsigned*)(colSum + (size_t)Nb * S);
    unsigned* colMax = rowMax + (size_t)Nb * L;
    unsigned* cnt    = colMax + (size_t)Nb * S;
    unsigned* cand   = cnt + 4;                        // 512 KB

    const int nStats = 2 * (Nb * L + Nb * S) + 4;      // sums + maxes + counter(+pad)
    const int n8 = Nb * L * C / 8;
    cvt_bf16<<<dim3((n8 + 255) / 256, 2), 256, 0, stream>>>(f0, f1, Abf, Bbf, n8,
                                                            (unsigned*)rowSum, nStats);

    gemm_pass<0><<<NWG, 256, 0, stream>>>(Abf, Bbf, rowSum, colSum,
                                          nullptr, mask, nullptr, nullptr, nullptr, nullptr);
    gemm_pass<1><<<NWG, 256, 0, stream>>>(Abf, Bbf, rowSum, colSum,
                                          conf, nullptr, rowMax, colMax, cnt, cand);

    mask_scatter<<<32, 256, 0, stream>>>(cnt, cand, rowMax, colMax, mask);
}

// Round 16
// 153.556 us; speedup vs baseline: 1.3076x; 1.3076x over previous
//
#include <hip/hip_runtime.h>
#include <hip/hip_bf16.h>
#include <cstdint>

static constexpr int   Nb = 2;
static constexpr int   L  = 4800;
static constexpr int   S  = 4800;
static constexpr int   C  = 256;
static constexpr float THR = 0.2f;
static constexpr float SIM_SCALE = 1.0f / 25.6f;   // 1/(sqrt(C)*sqrt(C)*TEMP)
static constexpr unsigned CAND_CAP = 65536;        // hard math bound is 38400 (<=4/row)

using f32x4  = __attribute__((ext_vector_type(4))) float;
using bf16x8 = __attribute__((ext_vector_type(8))) short;
using u32x4  = __attribute__((ext_vector_type(4))) unsigned int;

// ---------------- fp32 -> bf16 (RNE), both inputs; stats zeroing folded in ----------------
__device__ inline unsigned short bf16_rne(float x) {
    unsigned u = __float_as_uint(x);
    unsigned r = (u + 0x7FFFu + ((u >> 16) & 1u)) >> 16;
    return (unsigned short)r;
}

__global__ __launch_bounds__(256) void cvt_bf16(const float* __restrict__ in0,
                                                const float* __restrict__ in1,
                                                unsigned short* __restrict__ out0,
                                                unsigned short* __restrict__ out1,
                                                int n8,
                                                unsigned* __restrict__ stats, int nStats) {
    if (blockIdx.y == 0) {
        int si = blockIdx.x * 256 + threadIdx.x;
        if (si < nStats) stats[si] = 0u;
    }
    const float* in = blockIdx.y ? in1 : in0;
    unsigned short* out = blockIdx.y ? out1 : out0;
    int i = blockIdx.x * 256 + threadIdx.x;
    if (i >= n8) return;
    f32x4 a = *(const f32x4*)(in + (size_t)i * 8);
    f32x4 b = *(const f32x4*)(in + (size_t)i * 8 + 4);
    union { unsigned short us[8]; u32x4 v; } r;
#pragma unroll
    for (int j = 0; j < 4; j++) r.us[j] = bf16_rne(a[j]);
#pragma unroll
    for (int j = 0; j < 4; j++) r.us[4 + j] = bf16_rne(b[j]);
    *(u32x4*)(out + (size_t)i * 8) = r.v;
}

__device__ inline bool border_ok(int idx) {
    int h = idx / 80, w = idx % 80;
    return (h >= 2) & (h < 58) & (w >= 2) & (w < 78);
}

// ---------------- GEMM core, two epilogue modes ----------------
// R6 structure (best: 161.9 us) + NONTEMPORAL output stores.
// Tile 96x192, 4 waves (2x2), wave-tile 48x96 = 3x6 frags of mfma 16x16x32 bf16
// (swapped operands: lane&15 -> l, (lane>>4)*4+r -> s).
// Staging: global_load_lds dwordx4, pre-swizzled source, linear LDS dest,
// XOR-swizzled ds_read (rule-21 both-sides pattern).
// XCD-aware bijective block swizzle (T1/m204), rb-outer/cb-inner order (R12:
// ordering governs WRITE locality — concurrent blocks fill contiguous swaths).
// NEW: conf/mask streaming stores are NONTEMPORAL (never re-read; nt keeps the
// 368 MB/pass write stream from evicting the A/B staging panels out of L2 —
// the one mechanism invariant across all 8 prior structural variants).
// MODE 0: rowSum/colSum of exp(sim) + zero mask region.
// MODE 1: recompute; write conf + row/col bit-max + candidate list.
#define BM 96
#define BN 192
#define BK 64

static constexpr int NWG   = (L / BM) * (S / BN) * Nb;   // 2500
static constexpr int TILE_X = S / BN;                    // 25
static constexpr int TILES_PER_N = (L / BM) * TILE_X;    // 1250
static constexpr int XQ = NWG / 8;                       // 312
static constexpr int XR = NWG % 8;                       // 4

__device__ inline void gload16(const void* g, void* l) {
    __builtin_amdgcn_global_load_lds(
        (const __attribute__((address_space(1))) unsigned int*)g,
        (__attribute__((address_space(3))) unsigned int*)l, 16, 0, 0);
}

template <int MODE>
__global__ __launch_bounds__(256) void gemm_pass(
    const unsigned short* __restrict__ Abf,  // [N,L,C]
    const unsigned short* __restrict__ Bbf,  // [N,S,C]
    float* __restrict__ rowSum,              // [N,L]
    float* __restrict__ colSum,              // [N,S]
    float* __restrict__ conf,                // [N,L,S]      (MODE 1)
    float* __restrict__ mask,                // [N,L,S]      (MODE 0: zeroed here)
    unsigned* __restrict__ rowMax,           // [N,L] bits   (MODE 1)
    unsigned* __restrict__ colMax,           // [N,S] bits   (MODE 1)
    unsigned* __restrict__ cnt,              // cand count   (MODE 1)
    unsigned* __restrict__ cand)             // [CAP][2]     (MODE 1)
{
    __shared__ unsigned short As[BM * BK];   // 12 KB
    __shared__ unsigned short Bs[BN * BK];   // 24 KB

    // bijective XCD swizzle (m204): orig%8 -> xcd, contiguous wgid chunk per xcd
    const int orig = blockIdx.x;
    const int xcd  = orig & 7;
    const int idx  = orig >> 3;
    const int wgid = (xcd < XR ? xcd * (XQ + 1) : XR * (XQ + 1) + (xcd - XR) * XQ) + idx;
    const int n    = wgid / TILES_PER_N;
    const int rem  = wgid % TILES_PER_N;
    const int rb   = (rem / TILE_X) * BM;    // rb outer: concurrent blocks share a
    const int cb   = (rem % TILE_X) * BN;    // row-panel -> contiguous output swaths

    const int t  = threadIdx.x;
    const int lane = t & 63;
    const int wid  = t >> 6;
    const int wr = wid >> 1, wc = wid & 1;

    const unsigned short* Ag = Abf + ((size_t)n * L + rb) * C;
    const unsigned short* Bg = Bbf + ((size_t)n * S + cb) * C;

    f32x4 acc[3][6] = {};

    for (int kt = 0; kt < C; kt += BK) {
        // A: 768 16B chunks (3/thread), B: 1536 chunks (6/thread)
#pragma unroll
        for (int i = 0; i < 3; i++) {
            int ix = wid * 192 + i * 64 + lane;
            int row = ix >> 3;
            int src = ((ix & 7) ^ (row & 7)) * 8 + kt;
            gload16(Ag + (size_t)row * C + src, &As[(wid * 192 + i * 64) * 8]);
        }
#pragma unroll
        for (int i = 0; i < 6; i++) {
            int ix = wid * 384 + i * 64 + lane;
            int row = ix >> 3;
            int src = ((ix & 7) ^ (row & 7)) * 8 + kt;
            gload16(Bg + (size_t)row * C + src, &Bs[(wid * 384 + i * 64) * 8]);
        }
        __syncthreads();

#pragma unroll
        for (int kk = 0; kk < 2; kk++) {
            bf16x8 a[3], b[6];
            const int kElem = kk * 32 + (lane >> 4) * 8;
#pragma unroll
            for (int f = 0; f < 3; f++) {
                int ra = wr * 48 + f * 16 + (lane & 15);
                a[f] = *(const bf16x8*)&As[ra * 64 + (kElem ^ ((ra & 7) << 3))];
            }
#pragma unroll
            for (int f = 0; f < 6; f++) {
                int rbi = wc * 96 + f * 16 + (lane & 15);
                b[f] = *(const bf16x8*)&Bs[rbi * 64 + (kElem ^ ((rbi & 7) << 3))];
            }
#pragma unroll
            for (int fi = 0; fi < 3; fi++)
#pragma unroll
                for (int fj = 0; fj < 6; fj++)
                    acc[fi][fj] = __builtin_amdgcn_mfma_f32_16x16x32_bf16(
                        b[fj], a[fi], acc[fi][fj], 0, 0, 0);
        }
        __syncthreads();
    }

    const int rowBase = rb + wr * 48;
    const int colBase = cb + wc * 96;

    if constexpr (MODE == 0) {
        float csum[6][4] = {};
#pragma unroll
        for (int fi = 0; fi < 3; fi++) {
            const int l = rowBase + fi * 16 + (lane & 15);
            float rsum = 0.f;
#pragma unroll
            for (int fj = 0; fj < 6; fj++) {
#pragma unroll
                for (int r = 0; r < 4; r++) {
                    float e = __expf(acc[fi][fj][r] * SIM_SCALE);
                    rsum += e;
                    csum[fj][r] += e;
                }
            }
            rsum += __shfl_xor(rsum, 16);
            rsum += __shfl_xor(rsum, 32);
            if (lane < 16)
                atomicAdd(&rowSum[(size_t)n * L + l], rsum);
        }
#pragma unroll
        for (int fj = 0; fj < 6; fj++)
#pragma unroll
            for (int r = 0; r < 4; r++) {
                float v = csum[fj][r];
                v += __shfl_xor(v, 1);
                v += __shfl_xor(v, 2);
                v += __shfl_xor(v, 4);
                v += __shfl_xor(v, 8);
                if ((lane & 15) == 0)
                    atomicAdd(&colSum[(size_t)n * S + colBase + fj * 16 + ((lane >> 4) << 2) + r], v);
            }
        // zero this block's linear chunk of the mask region — NONTEMPORAL
        const f32x4 zero4 = {0.f, 0.f, 0.f, 0.f};
        const size_t mbase = (size_t)wgid * 18432;   // 46.08M / 2500 blocks
#pragma unroll
        for (int i = 0; i < 18; i++)
            __builtin_nontemporal_store(zero4, (f32x4*)&mask[mbase + ((size_t)i * 256 + t) * 4]);
    } else {
        f32x4 invD1[6];
#pragma unroll
        for (int fj = 0; fj < 6; fj++) {
            const int s0 = colBase + fj * 16 + ((lane >> 4) << 2);
            f32x4 d1 = *(const f32x4*)&colSum[(size_t)n * S + s0];
#pragma unroll
            for (int j = 0; j < 4; j++) invD1[fj][j] = 1.0f / d1[j];
        }
        float cmax[6][4] = {};

#pragma unroll
        for (int fi = 0; fi < 3; fi++) {
            const int l = rowBase + fi * 16 + (lane & 15);
            const float invD2 = 1.0f / rowSum[(size_t)n * L + l];
            const bool bl = border_ok(l);
            float rmax = 0.f;
#pragma unroll
            for (int fj = 0; fj < 6; fj++) {
                const int s0 = colBase + fj * 16 + ((lane >> 4) << 2);
                f32x4 cv;
#pragma unroll
                for (int r = 0; r < 4; r++) {
                    float e = __expf(acc[fi][fj][r] * SIM_SCALE);
                    float c = e * e * invD1[fj][r] * invD2;
                    cv[r] = c;
                    rmax = fmaxf(rmax, c);
                    cmax[fj][r] = fmaxf(cmax[fj][r], c);
                    if (c > THR) {                       // rare: <=4 per row possible
                        int s = s0 + r;
                        if (bl && border_ok(s)) {
                            unsigned pos = atomicAdd(cnt, 1u);
                            if (pos < CAND_CAP) {
                                cand[2 * pos]     = (unsigned)(((size_t)n * L + l) * S + s);
                                cand[2 * pos + 1] = __float_as_uint(c);
                            }
                        }
                    }
                }
                __builtin_nontemporal_store(cv, (f32x4*)&conf[((size_t)n * L + l) * S + s0]);
            }
            rmax = fmaxf(rmax, __shfl_xor(rmax, 16));
            rmax = fmaxf(rmax, __shfl_xor(rmax, 32));
            if (lane < 16)
                atomicMax(&rowMax[(size_t)n * L + l], __float_as_uint(rmax));
        }
#pragma unroll
        for (int fj = 0; fj < 6; fj++)
#pragma unroll
            for (int r = 0; r < 4; r++) {
                float v = cmax[fj][r];
                v = fmaxf(v, __shfl_xor(v, 1));
                v = fmaxf(v, __shfl_xor(v, 2));
                v = fmaxf(v, __shfl_xor(v, 4));
                v = fmaxf(v, __shfl_xor(v, 8));
                if ((lane & 15) == 0)
                    atomicMax(&colMax[(size_t)n * S + colBase + fj * 16 + ((lane >> 4) << 2) + r],
                              __float_as_uint(v));
            }
    }
}

// ---------------- scatter the mutual-NN survivors ----------------
__global__ __launch_bounds__(256) void mask_scatter(
    const unsigned* __restrict__ cnt,
    const unsigned* __restrict__ cand,
    const unsigned* __restrict__ rowMax,
    const unsigned* __restrict__ colMax,
    float* __restrict__ mask)
{
    unsigned nc = *cnt;
    if (nc > CAND_CAP) nc = CAND_CAP;
    for (unsigned i = blockIdx.x * 256 + threadIdx.x; i < nc; i += gridDim.x * 256) {
        unsigned flat = cand[2 * i];
        unsigned bits = cand[2 * i + 1];
        unsigned row = flat / S;          // n*L + l
        unsigned s   = flat % S;
        unsigned n   = row / L;
        if (bits == rowMax[row] && bits == colMax[n * S + s])
            mask[flat] = 1.0f;
    }
}

// ---------------- launch ----------------
extern "C" void kernel_launch(void* const* d_in, const int* in_sizes, int n_in,
                              void* d_out, int out_size, void* d_ws, size_t ws_size,
                              hipStream_t stream) {
    (void)in_sizes; (void)n_in; (void)out_size; (void)ws_size;
    const float* f0 = (const float*)d_in[0];
    const float* f1 = (const float*)d_in[1];

    float* conf = (float*)d_out;                       // N*L*S f32
    float* mask = conf + (size_t)Nb * L * S;

    unsigned short* Abf = (unsigned short*)d_ws;       // 4.92 MB
    unsigned short* Bbf = Abf + (size_t)Nb * L * C;    // 4.92 MB
    float* rowSum = (float*)(Bbf + (size_t)Nb * S * C);
    float* colSum = rowSum + (size_t)Nb * L;
    unsigned* rowMax = (unsigned*)(colSum + (size_t)Nb * S);
    unsigned* colMax = rowMax + (size_t)Nb * L;
    unsigned* cnt    = colMax + (size_t)Nb * S;
    unsigned* cand   = cnt + 4;                        // 512 KB

    const int nStats = 2 * (Nb * L + Nb * S) + 4;      // sums + maxes + counter(+pad)
    const int n8 = Nb * L * C / 8;
    cvt_bf16<<<dim3((n8 + 255) / 256, 2), 256, 0, stream>>>(f0, f1, Abf, Bbf, n8,
                                                            (unsigned*)rowSum, nStats);

    gemm_pass<0><<<NWG, 256, 0, stream>>>(Abf, Bbf, rowSum, colSum,
                                          nullptr, mask, nullptr, nullptr, nullptr, nullptr);
    gemm_pass<1><<<NWG, 256, 0, stream>>>(Abf, Bbf, rowSum, colSum,
                                          conf, nullptr, rowMax, colMax, cnt, cand);

    mask_scatter<<<32, 256, 0, stream>>>(cnt, cand, rowMax, colMax, mask);
}

// Round 17
// 143.003 us; speedup vs baseline: 1.4041x; 1.0738x over previous
//
#include <hip/hip_runtime.h>
#include <hip/hip_bf16.h>
#include <cstdint>

static constexpr int   Nb = 2;
static constexpr int   L  = 4800;
static constexpr int   S  = 4800;
static constexpr int   C  = 256;
static constexpr float THR = 0.2f;
static constexpr float SIM_SCALE = 1.0f / 25.6f;   // 1/(sqrt(C)*sqrt(C)*TEMP)
static constexpr unsigned CAND_CAP = 65536;        // hard math bound is 38400 (<=4/row)

using f32x4  = __attribute__((ext_vector_type(4))) float;
using bf16x8 = __attribute__((ext_vector_type(8))) short;
using u32x4  = __attribute__((ext_vector_type(4))) unsigned int;

// ---------------- fp32 -> bf16 (RNE), both inputs; stats zeroing folded in ----------------
__device__ inline unsigned short bf16_rne(float x) {
    unsigned u = __float_as_uint(x);
    unsigned r = (u + 0x7FFFu + ((u >> 16) & 1u)) >> 16;
    return (unsigned short)r;
}

__global__ __launch_bounds__(256) void cvt_bf16(const float* __restrict__ in0,
                                                const float* __restrict__ in1,
                                                unsigned short* __restrict__ out0,
                                                unsigned short* __restrict__ out1,
                                                int n8,
                                                unsigned* __restrict__ stats, int nStats) {
    if (blockIdx.y == 0) {
        int si = blockIdx.x * 256 + threadIdx.x;
        if (si < nStats) stats[si] = 0u;
    }
    const float* in = blockIdx.y ? in1 : in0;
    unsigned short* out = blockIdx.y ? out1 : out0;
    int i = blockIdx.x * 256 + threadIdx.x;
    if (i >= n8) return;
    f32x4 a = *(const f32x4*)(in + (size_t)i * 8);
    f32x4 b = *(const f32x4*)(in + (size_t)i * 8 + 4);
    union { unsigned short us[8]; u32x4 v; } r;
#pragma unroll
    for (int j = 0; j < 4; j++) r.us[j] = bf16_rne(a[j]);
#pragma unroll
    for (int j = 0; j < 4; j++) r.us[4 + j] = bf16_rne(b[j]);
    *(u32x4*)(out + (size_t)i * 8) = r.v;
}

__device__ inline bool border_ok(int idx) {
    int h = idx / 80, w = idx % 80;
    return (h >= 2) & (h < 58) & (w >= 2) & (w < 78);
}

// ---------------- GEMM core, two epilogue modes ----------------
// R16 structure (best: 153.6 us) with 8-WAVE 512-thread blocks for occupancy.
// Tile 96x192, 8 waves (2x4), wave-tile 48x48 = 3x3 frags of mfma 16x16x32 bf16
// (swapped operands: lane&15 -> l, (lane>>4)*4+r -> s). acc = 36 VGPR/wave ->
// ~100 total, __launch_bounds__(512,4) caps 128 -> 2 blocks/CU = 16 waves/CU
// (+33% TLP over R16's 12; epilogue writes overlap other waves' MFMA better).
// Staging: global_load_lds dwordx4, pre-swizzled source, linear LDS dest,
// XOR-swizzled ds_read (rule-21). Waves 0-3 stage A (3 gloads/thr),
// waves 4-7 stage B (6 gloads/thr).
// XCD-aware bijective block swizzle (T1/m204), rb-outer/cb-inner (R12: write
// locality). Output stores NONTEMPORAL (R16: +5%, keeps staging in L2).
// MODE 0: rowSum/colSum of exp(sim) + zero mask region.
// MODE 1: recompute; write conf + row/col bit-max + candidate list.
#define BM 96
#define BN 192
#define BK 64

static constexpr int NWG   = (L / BM) * (S / BN) * Nb;   // 2500
static constexpr int TILE_X = S / BN;                    // 25
static constexpr int TILES_PER_N = (L / BM) * TILE_X;    // 1250
static constexpr int XQ = NWG / 8;                       // 312
static constexpr int XR = NWG % 8;                       // 4

__device__ inline void gload16(const void* g, void* l) {
    __builtin_amdgcn_global_load_lds(
        (const __attribute__((address_space(1))) unsigned int*)g,
        (__attribute__((address_space(3))) unsigned int*)l, 16, 0, 0);
}

template <int MODE>
__global__ __launch_bounds__(512, 4) void gemm_pass(
    const unsigned short* __restrict__ Abf,  // [N,L,C]
    const unsigned short* __restrict__ Bbf,  // [N,S,C]
    float* __restrict__ rowSum,              // [N,L]
    float* __restrict__ colSum,              // [N,S]
    float* __restrict__ conf,                // [N,L,S]      (MODE 1)
    float* __restrict__ mask,                // [N,L,S]      (MODE 0: zeroed here)
    unsigned* __restrict__ rowMax,           // [N,L] bits   (MODE 1)
    unsigned* __restrict__ colMax,           // [N,S] bits   (MODE 1)
    unsigned* __restrict__ cnt,              // cand count   (MODE 1)
    unsigned* __restrict__ cand)             // [CAP][2]     (MODE 1)
{
    __shared__ unsigned short As[BM * BK];   // 12 KB
    __shared__ unsigned short Bs[BN * BK];   // 24 KB

    // bijective XCD swizzle (m204): orig%8 -> xcd, contiguous wgid chunk per xcd
    const int orig = blockIdx.x;
    const int xcd  = orig & 7;
    const int idx  = orig >> 3;
    const int wgid = (xcd < XR ? xcd * (XQ + 1) : XR * (XQ + 1) + (xcd - XR) * XQ) + idx;
    const int n    = wgid / TILES_PER_N;
    const int rem  = wgid % TILES_PER_N;
    const int rb   = (rem / TILE_X) * BM;    // rb outer: concurrent blocks share a
    const int cb   = (rem % TILE_X) * BN;    // row-panel -> contiguous output swaths

    const int t  = threadIdx.x;
    const int lane = t & 63;
    const int wid  = t >> 6;                 // 0..7
    const int wr = wid >> 2, wc = wid & 3;   // wave grid 2x4, wave-tile 48x48

    const unsigned short* Ag = Abf + ((size_t)n * L + rb) * C;
    const unsigned short* Bg = Bbf + ((size_t)n * S + cb) * C;

    f32x4 acc[3][3] = {};

    for (int kt = 0; kt < C; kt += BK) {
        // A: 768 16B chunks by waves 0-3 (3/thr); B: 1536 chunks by waves 4-7 (6/thr)
        if (wid < 4) {
#pragma unroll
            for (int i = 0; i < 3; i++) {
                int ix = wid * 192 + i * 64 + lane;
                int row = ix >> 3;
                int src = ((ix & 7) ^ (row & 7)) * 8 + kt;
                gload16(Ag + (size_t)row * C + src, &As[(wid * 192 + i * 64) * 8]);
            }
        } else {
            const int w = wid - 4;
#pragma unroll
            for (int i = 0; i < 6; i++) {
                int ix = w * 384 + i * 64 + lane;
                int row = ix >> 3;
                int src = ((ix & 7) ^ (row & 7)) * 8 + kt;
                gload16(Bg + (size_t)row * C + src, &Bs[(w * 384 + i * 64) * 8]);
            }
        }
        __syncthreads();

#pragma unroll
        for (int kk = 0; kk < 2; kk++) {
            bf16x8 a[3], b[3];
            const int kElem = kk * 32 + (lane >> 4) * 8;
#pragma unroll
            for (int f = 0; f < 3; f++) {
                int ra = wr * 48 + f * 16 + (lane & 15);
                a[f] = *(const bf16x8*)&As[ra * 64 + (kElem ^ ((ra & 7) << 3))];
            }
#pragma unroll
            for (int f = 0; f < 3; f++) {
                int rbi = wc * 48 + f * 16 + (lane & 15);
                b[f] = *(const bf16x8*)&Bs[rbi * 64 + (kElem ^ ((rbi & 7) << 3))];
            }
#pragma unroll
            for (int fi = 0; fi < 3; fi++)
#pragma unroll
                for (int fj = 0; fj < 3; fj++)
                    acc[fi][fj] = __builtin_amdgcn_mfma_f32_16x16x32_bf16(
                        b[fj], a[fi], acc[fi][fj], 0, 0, 0);
        }
        __syncthreads();
    }

    const int rowBase = rb + wr * 48;
    const int colBase = cb + wc * 48;

    if constexpr (MODE == 0) {
        float csum[3][4] = {};
#pragma unroll
        for (int fi = 0; fi < 3; fi++) {
            const int l = rowBase + fi * 16 + (lane & 15);
            float rsum = 0.f;
#pragma unroll
            for (int fj = 0; fj < 3; fj++) {
#pragma unroll
                for (int r = 0; r < 4; r++) {
                    float e = __expf(acc[fi][fj][r] * SIM_SCALE);
                    rsum += e;
                    csum[fj][r] += e;
                }
            }
            rsum += __shfl_xor(rsum, 16);
            rsum += __shfl_xor(rsum, 32);
            if (lane < 16)
                atomicAdd(&rowSum[(size_t)n * L + l], rsum);
        }
#pragma unroll
        for (int fj = 0; fj < 3; fj++)
#pragma unroll
            for (int r = 0; r < 4; r++) {
                float v = csum[fj][r];
                v += __shfl_xor(v, 1);
                v += __shfl_xor(v, 2);
                v += __shfl_xor(v, 4);
                v += __shfl_xor(v, 8);
                if ((lane & 15) == 0)
                    atomicAdd(&colSum[(size_t)n * S + colBase + fj * 16 + ((lane >> 4) << 2) + r], v);
            }
        // zero this block's linear chunk of the mask region — NONTEMPORAL
        const f32x4 zero4 = {0.f, 0.f, 0.f, 0.f};
        const size_t mbase = (size_t)wgid * 18432;   // 46.08M / 2500 blocks
#pragma unroll
        for (int i = 0; i < 9; i++)
            __builtin_nontemporal_store(zero4, (f32x4*)&mask[mbase + ((size_t)i * 512 + t) * 4]);
    } else {
        f32x4 invD1[3];
#pragma unroll
        for (int fj = 0; fj < 3; fj++) {
            const int s0 = colBase + fj * 16 + ((lane >> 4) << 2);
            f32x4 d1 = *(const f32x4*)&colSum[(size_t)n * S + s0];
#pragma unroll
            for (int j = 0; j < 4; j++) invD1[fj][j] = 1.0f / d1[j];
        }
        float cmax[3][4] = {};

#pragma unroll
        for (int fi = 0; fi < 3; fi++) {
            const int l = rowBase + fi * 16 + (lane & 15);
            const float invD2 = 1.0f / rowSum[(size_t)n * L + l];
            const bool bl = border_ok(l);
            float rmax = 0.f;
#pragma unroll
            for (int fj = 0; fj < 3; fj++) {
                const int s0 = colBase + fj * 16 + ((lane >> 4) << 2);
                f32x4 cv;
#pragma unroll
                for (int r = 0; r < 4; r++) {
                    float e = __expf(acc[fi][fj][r] * SIM_SCALE);
                    float c = e * e * invD1[fj][r] * invD2;
                    cv[r] = c;
                    rmax = fmaxf(rmax, c);
                    cmax[fj][r] = fmaxf(cmax[fj][r], c);
                    if (c > THR) {                       // rare: <=4 per row possible
                        int s = s0 + r;
                        if (bl && border_ok(s)) {
                            unsigned pos = atomicAdd(cnt, 1u);
                            if (pos < CAND_CAP) {
                                cand[2 * pos]     = (unsigned)(((size_t)n * L + l) * S + s);
                                cand[2 * pos + 1] = __float_as_uint(c);
                            }
                        }
                    }
                }
                __builtin_nontemporal_store(cv, (f32x4*)&conf[((size_t)n * L + l) * S + s0]);
            }
            rmax = fmaxf(rmax, __shfl_xor(rmax, 16));
            rmax = fmaxf(rmax, __shfl_xor(rmax, 32));
            if (lane < 16)
                atomicMax(&rowMax[(size_t)n * L + l], __float_as_uint(rmax));
        }
#pragma unroll
        for (int fj = 0; fj < 3; fj++)
#pragma unroll
            for (int r = 0; r < 4; r++) {
                float v = cmax[fj][r];
                v = fmaxf(v, __shfl_xor(v, 1));
                v = fmaxf(v, __shfl_xor(v, 2));
                v = fmaxf(v, __shfl_xor(v, 4));
                v = fmaxf(v, __shfl_xor(v, 8));
                if ((lane & 15) == 0)
                    atomicMax(&colMax[(size_t)n * S + colBase + fj * 16 + ((lane >> 4) << 2) + r],
                              __float_as_uint(v));
            }
    }
}

// ---------------- scatter the mutual-NN survivors ----------------
__global__ __launch_bounds__(256) void mask_scatter(
    const unsigned* __restrict__ cnt,
    const unsigned* __restrict__ cand,
    const unsigned* __restrict__ rowMax,
    const unsigned* __restrict__ colMax,
    float* __restrict__ mask)
{
    unsigned nc = *cnt;
    if (nc > CAND_CAP) nc = CAND_CAP;
    for (unsigned i = blockIdx.x * 256 + threadIdx.x; i < nc; i += gridDim.x * 256) {
        unsigned flat = cand[2 * i];
        unsigned bits = cand[2 * i + 1];
        unsigned row = flat / S;          // n*L + l
        unsigned s   = flat % S;
        unsigned n   = row / L;
        if (bits == rowMax[row] && bits == colMax[n * S + s])
            mask[flat] = 1.0f;
    }
}

// ---------------- launch ----------------
extern "C" void kernel_launch(void* const* d_in, const int* in_sizes, int n_in,
                              void* d_out, int out_size, void* d_ws, size_t ws_size,
                              hipStream_t stream) {
    (void)in_sizes; (void)n_in; (void)out_size; (void)ws_size;
    const float* f0 = (const float*)d_in[0];
    const float* f1 = (const float*)d_in[1];

    float* conf = (float*)d_out;                       // N*L*S f32
    float* mask = conf + (size_t)Nb * L * S;

    unsigned short* Abf = (unsigned short*)d_ws;       // 4.92 MB
    unsigned short* Bbf = Abf + (size_t)Nb * L * C;    // 4.92 MB
    float* rowSum = (float*)(Bbf + (size_t)Nb * S * C);
    float* colSum = rowSum + (size_t)Nb * L;
    unsigned* rowMax = (unsigned*)(colSum + (size_t)Nb * S);
    unsigned* colMax = rowMax + (size_t)Nb * L;
    unsigned* cnt    = colMax + (size_t)Nb * S;
    unsigned* cand   = cnt + 4;                        // 512 KB

    const int nStats = 2 * (Nb * L + Nb * S) + 4;      // sums + maxes + counter(+pad)
    const int n8 = Nb * L * C / 8;
    cvt_bf16<<<dim3((n8 + 255) / 256, 2), 256, 0, stream>>>(f0, f1, Abf, Bbf, n8,
                                                            (unsigned*)rowSum, nStats);

    gemm_pass<0><<<NWG, 512, 0, stream>>>(Abf, Bbf, rowSum, colSum,
                                          nullptr, mask, nullptr, nullptr, nullptr, nullptr);
    gemm_pass<1><<<NWG, 512, 0, stream>>>(Abf, Bbf, rowSum, colSum,
                                          conf, nullptr, rowMax, colMax, cnt, cand);

    mask_scatter<<<32, 256, 0, stream>>>(cnt, cand, rowMax, colMax, mask);
}